// Round 3
// baseline (414.198 us; speedup 1.0000x reference)
//
#include <hip/hip_runtime.h>
#include <cstdint>
#include <cstddef>

#define VV 4
#define NN 2048
#define DDIM 128
#define KK 10
#define CAP 256

__device__ __forceinline__ bool kgt(float v1, int i1, float v0, int i0) {
  // strict "greater" in top-k order: larger value wins; ties -> smaller index wins
  return (v1 > v0) || (v1 == v0 && i1 < i0);
}

struct ProjSm { float As[16][DDIM]; float s_mv[2][DDIM]; };
struct TopkSm { float s_val[4][CAP]; int s_idx[4][CAP]; unsigned s_cnt[4]; };
union SmU { ProjSm p; TopkSm t; };

// ---------------------------------------------------------------------------
// Kernel 1 (heterogeneous): blocks 0..511 do per-view projections (W rows held
// in registers — no LDS round-trip, one barrier); blocks 512..6655 do the
// HBM-bound C top-10 scan. Independent work co-scheduled in one dispatch so
// proj VALU hides under the C stream.
// ---------------------------------------------------------------------------
__global__ __launch_bounds__(256) void proj_topk_kernel(
    const float* __restrict__ A, const float* __restrict__ WQ,
    const float* __restrict__ WK, const float* __restrict__ WV,
    const float* __restrict__ C,
    float* __restrict__ Qn, float* __restrict__ Kn, float* __restrict__ Vn,
    float* __restrict__ partialMV, int* __restrict__ topIdx)
{
  __shared__ SmU sm;
  const int t = threadIdx.x;

  if (blockIdx.x < 512) {
    // ======================= projection path =======================
    const int v    = blockIdx.x >> 7;          // /128
    const int blk  = blockIdx.x & 127;
    const int n0   = blk * 16;
    const int e    = t & 127;
    const int half = t >> 7;

    // stage A tile (16 rows x 128) once
    const float* Ab = A + ((size_t)v * NN + n0) * DDIM;
#pragma unroll
    for (int k = 0; k < 2; ++k) {
      int id4 = k * 256 + t;                   // 0..511
      int r   = id4 >> 5;
      int d4  = id4 & 31;
      float4 a4 = *(const float4*)(Ab + (size_t)id4 * 4);
      *(float4*)&sm.p.As[r][d4 * 4] = a4;
    }
    __syncthreads();

    float accq[8], acck[8], accv[8];
#pragma unroll
    for (int r = 0; r < 8; ++r) { accq[r] = 0.f; acck[r] = 0.f; accv[r] = 0.f; }

    // this thread's W rows (output column e of each matrix)
    const float* wqr = WQ + ((size_t)v * DDIM + e) * DDIM;
    const float* wkr = WK + ((size_t)v * DDIM + e) * DDIM;
    const float* wvr = WV + ((size_t)v * DDIM + e) * DDIM;

    for (int d0 = 0; d0 < DDIM; d0 += 16) {
      float4 wq4[4], wk4[4], wv4[4];
#pragma unroll
      for (int c4 = 0; c4 < 4; ++c4) {
        wq4[c4] = *(const float4*)(wqr + d0 + c4 * 4);
        wk4[c4] = *(const float4*)(wkr + d0 + c4 * 4);
        wv4[c4] = *(const float4*)(wvr + d0 + c4 * 4);
      }
#pragma unroll
      for (int g = 0; g < 4; ++g) {            // dd = 4*g
        float4 a4[8];
#pragma unroll
        for (int r = 0; r < 8; ++r)
          a4[r] = *(const float4*)&sm.p.As[half * 8 + r][d0 + g * 4];  // broadcast
#pragma unroll
        for (int c = 0; c < 4; ++c) {
          const float wq = ((const float*)&wq4[g])[c];
          const float wk = ((const float*)&wk4[g])[c];
          const float wv = ((const float*)&wv4[g])[c];
#pragma unroll
          for (int r = 0; r < 8; ++r) {
            const float av = ((const float*)&a4[r])[c];
            accq[r] = fmaf(av, wq, accq[r]);
            acck[r] = fmaf(av, wk, acck[r]);
            accv[r] = fmaf(av, wv, accv[r]);
          }
        }
      }
    }

    const size_t ob = ((size_t)v * NN + n0 + half * 8) * DDIM + e;
#pragma unroll
    for (int r = 0; r < 8; ++r) {
      Qn[ob + (size_t)r * DDIM] = accq[r];
      Kn[ob + (size_t)r * DDIM] = acck[r];
      Vn[ob + (size_t)r * DDIM] = accv[r];
    }
    float s = 0.f;
#pragma unroll
    for (int r = 0; r < 8; ++r) s += accv[r];
    sm.p.s_mv[half][e] = s;
    __syncthreads();
    if (half == 0)
      partialMV[((size_t)v * 128 + blk) * DDIM + e] = s + sm.p.s_mv[1][e];

  } else {
    // ======================= top-k path =======================
    const int w    = t >> 6;
    const int lane = t & 63;
    const int task = (blockIdx.x - 512) * 4 + w;   // 0..24575
    const int pq   = task >> 11;                   // 0..11
    const int n    = task & 2047;
    const int p    = (pq * 11) >> 5;               // pq / 3 for pq < 12
    const int o    = pq - p * 3;
    const int q    = o + (o >= p ? 1 : 0);

    const float* row = C + (((size_t)(p * 4 + q) * NN + n) << 11);
    float4 vv[8];
#pragma unroll
    for (int i = 0; i < 8; ++i) vv[i] = *(const float4*)(row + i * 256 + lane * 4);
    if (lane == 0) sm.t.s_cnt[w] = 0u;

    const float T1 = 0.99f, T2 = 0.95f;
    int c1 = 0;
#pragma unroll
    for (int i = 0; i < 8; ++i) {
      const float* pv = (const float*)&vv[i];
#pragma unroll
      for (int c = 0; c < 4; ++c) c1 += (pv[c] > T1) ? 1 : 0;
    }
#pragma unroll
    for (int off = 32; off; off >>= 1) c1 += __shfl_xor(c1, off);

    float T = T1; int cnt = c1; bool ok = (c1 >= KK && c1 <= CAP);
    if (!ok) {                                  // rare tier 2
      int c2 = 0;
#pragma unroll
      for (int i = 0; i < 8; ++i) {
        const float* pv = (const float*)&vv[i];
#pragma unroll
        for (int c = 0; c < 4; ++c) c2 += (pv[c] > T2) ? 1 : 0;
      }
#pragma unroll
      for (int off = 32; off; off >>= 1) c2 += __shfl_xor(c2, off);
      T = T2; cnt = c2; ok = (c2 >= KK && c2 <= CAP);
    }

    int* outp = topIdx + (size_t)task * KK;

    if (ok) {
#pragma unroll
      for (int i = 0; i < 8; ++i) {
        const float* pv = (const float*)&vv[i];
#pragma unroll
        for (int c = 0; c < 4; ++c) {
          float x = pv[c];
          if (x > T) {
            unsigned pos = atomicAdd(&sm.t.s_cnt[w], 1u);
            sm.t.s_val[w][pos] = x;
            sm.t.s_idx[w][pos] = i * 256 + lane * 4 + c;
          }
        }
      }
      __threadfence_block();
      if (cnt <= 64) {
        // 64-lane bitonic sort, descending by (value, then smaller index)
        float kv = (lane < cnt) ? sm.t.s_val[w][lane] : -1e30f;
        int   ki = (lane < cnt) ? sm.t.s_idx[w][lane] : 0x7FFFFFFF;
#pragma unroll
        for (int k = 2; k <= 64; k <<= 1) {
#pragma unroll
          for (int j = k >> 1; j > 0; j >>= 1) {
            float ov = __shfl_xor(kv, j);
            int   oi = __shfl_xor(ki, j);
            bool dirDesc = (lane & k) == 0;
            bool lower   = (lane & j) == 0;
            bool ogt     = (ov > kv) || (ov == kv && oi < ki);
            bool take    = (dirDesc == lower) ? ogt : !ogt;
            if (take) { kv = ov; ki = oi; }
          }
        }
        if (lane < KK) outp[lane] = ki;
      } else {
        // 65..256 candidates: 10 rounds of wave-argmax over 4 slots/lane
        float rv[4]; int ri[4];
#pragma unroll
        for (int s = 0; s < 4; ++s) {
          int  sl = lane + s * 64;
          bool in = sl < cnt;
          rv[s] = in ? sm.t.s_val[w][sl] : -1e30f;
          ri[s] = in ? sm.t.s_idx[w][sl] : 0x7FFFFFFF;
        }
        for (int r = 0; r < KK; ++r) {
          float lv = rv[0]; int li = ri[0]; int ls = 0;
#pragma unroll
          for (int s = 1; s < 4; ++s)
            if (kgt(rv[s], ri[s], lv, li)) { lv = rv[s]; li = ri[s]; ls = s; }
          float mv = lv; int mi = li;
#pragma unroll
          for (int off = 1; off < 64; off <<= 1) {
            float ov = __shfl_xor(mv, off);
            int   oi = __shfl_xor(mi, off);
            if (kgt(ov, oi, mv, mi)) { mv = ov; mi = oi; }
          }
          if (lane == 0) outp[r] = mi;
          if (li == mi) {
#pragma unroll
            for (int s = 0; s < 4; ++s)
              if (ls == s) { rv[s] = -1e30f; ri[s] = 0x7FFFFFFF; }
          }
        }
      }
    } else {
      // fully general fallback (distribution-independent, ~never taken)
      unsigned consumed = 0;
      for (int r = 0; r < KK; ++r) {
        float lv = -1e30f; int li = 0x7FFFFFFF; int ls = 0;
#pragma unroll
        for (int i = 0; i < 8; ++i) {
          const float* pv = (const float*)&vv[i];
#pragma unroll
          for (int c = 0; c < 4; ++c) {
            int   sl = i * 4 + c;
            float x  = ((consumed >> sl) & 1u) ? -1e30f : pv[c];
            int   ix = i * 256 + lane * 4 + c;
            if (kgt(x, ix, lv, li)) { lv = x; li = ix; ls = sl; }
          }
        }
        float mv = lv; int mi = li;
#pragma unroll
        for (int off = 1; off < 64; off <<= 1) {
          float ov = __shfl_xor(mv, off);
          int   oi = __shfl_xor(mi, off);
          if (kgt(ov, oi, mv, mi)) { mv = ov; mi = oi; }
        }
        if (lane == 0) outp[r] = mi;
        if (li == mi) consumed |= (1u << ls);
      }
    }
  }
}

// ---------------------------------------------------------------------------
// Kernel 2: meanV reduction + scores + softmax(10) + aggregate.
// One wave per (p,n). 2048 blocks x 256 thr; all 4 waves of a block share p.
// ---------------------------------------------------------------------------
__global__ __launch_bounds__(256) void agg_kernel(
    const float* __restrict__ Qn, const float* __restrict__ Kn,
    const float* __restrict__ Vn, const float* __restrict__ partialMV,
    const int* __restrict__ topIdx, float* __restrict__ out)
{
  __shared__ float s_sc[4][32];
  __shared__ float s_al[4][32];
  __shared__ float s_mvp[2][DDIM];
  __shared__ float s_mv[DDIM];

  const int t    = threadIdx.x;
  const int w    = t >> 6;
  const int lane = t & 63;
  const int task = blockIdx.x * 4 + w;       // 0..8191
  const int p    = task >> 11;               // same for all 4 waves of a block
  const int n    = task & 2047;
  const float SCALE = 0.08838834764831845f;  // 1/sqrt(128)

  // ---- block-cooperative meanV[p] from proj partials (128 x 128 floats) ----
  {
    const int e    = t & 127;
    const int half = t >> 7;
    const float* pb = partialMV + (size_t)p * 128 * DDIM;
    float sum = 0.f;
    for (int b = half * 64; b < half * 64 + 64; ++b)
      sum += pb[(size_t)b * DDIM + e];
    s_mvp[half][e] = sum;
    __syncthreads();
    if (half == 0) s_mv[e] = (s_mvp[0][e] + s_mvp[1][e]) * (1.0f / 2048.0f);
    __syncthreads();
  }

  const float* qrow = Qn + ((size_t)p * NN + n) * DDIM;
  const float q0 = qrow[lane];
  const float q1 = qrow[lane + 64];

  int mAll[30];
#pragma unroll
  for (int o = 0; o < 3; ++o) {
    const int* ip = topIdx + ((size_t)((p * 3 + o) * NN + n)) * KK;
#pragma unroll
    for (int j = 0; j < KK; ++j) mAll[o * KK + j] = ip[j];
  }

#pragma unroll
  for (int o = 0; o < 3; ++o) {
    const int q = o + (o >= p ? 1 : 0);
    const float* Kb = Kn + (size_t)q * NN * DDIM;
#pragma unroll
    for (int j = 0; j < KK; ++j) {
      const float* kr = Kb + (size_t)mAll[o * KK + j] * DDIM;
      float s = q0 * kr[lane] + q1 * kr[lane + 64];
#pragma unroll
      for (int off = 32; off; off >>= 1) s += __shfl_xor(s, off);
      if (lane == 0) s_sc[w][o * KK + j] = s * SCALE;
    }
  }
  __threadfence_block();

  if (lane < 30) {
    const int b = (lane / KK) * KK;
    float m = s_sc[w][b];
#pragma unroll
    for (int j = 1; j < KK; ++j) m = fmaxf(m, s_sc[w][b + j]);
    float den = 0.f;
#pragma unroll
    for (int j = 0; j < KK; ++j) den += expf(s_sc[w][b + j] - m);
    s_al[w][lane] = expf(s_sc[w][lane] - m) / den;
  }
  __threadfence_block();

  float acc0 = s_mv[lane];
  float acc1 = s_mv[lane + 64];
#pragma unroll
  for (int o = 0; o < 3; ++o) {
    const int q = o + (o >= p ? 1 : 0);
    const float* Vb = Vn + (size_t)q * NN * DDIM;
#pragma unroll
    for (int j = 0; j < KK; ++j) {
      const float a = s_al[w][o * KK + j];
      const float* vr = Vb + (size_t)mAll[o * KK + j] * DDIM;
      acc0 = fmaf(a, vr[lane], acc0);
      acc1 = fmaf(a, vr[lane + 64], acc1);
    }
  }
  float* orow = out + ((size_t)p * NN + n) * DDIM;
  orow[lane]      = acc0;
  orow[lane + 64] = acc1;
}

// ---------------------------------------------------------------------------
extern "C" void kernel_launch(void* const* d_in, const int* in_sizes, int n_in,
                              void* d_out, int out_size, void* d_ws, size_t ws_size,
                              hipStream_t stream)
{
  const float* A  = (const float*)d_in[0];
  const float* C  = (const float*)d_in[1];
  const float* WQ = (const float*)d_in[2];
  const float* WK = (const float*)d_in[3];
  const float* WV = (const float*)d_in[4];
  float* out = (float*)d_out;

  char* ws = (char*)d_ws;
  float* Qn        = (float*)ws;                               // 4 MB
  float* Kn        = (float*)(ws + (size_t)4 * 1024 * 1024);   // 4 MB
  float* Vn        = (float*)(ws + (size_t)8 * 1024 * 1024);   // 4 MB
  float* partialMV = (float*)(ws + (size_t)12 * 1024 * 1024);  // 256 KB
  int*   topIdx    = (int*)(ws + (size_t)12 * 1024 * 1024 + 256 * 1024); // 960 KB

  hipLaunchKernelGGL(proj_topk_kernel, dim3(6656), dim3(256), 0, stream,
                     A, WQ, WK, WV, C, Qn, Kn, Vn, partialMV, topIdx);
  hipLaunchKernelGGL(agg_kernel, dim3(2048), dim3(256), 0, stream,
                     Qn, Kn, Vn, partialMV, topIdx, out);
}